// Round 2
// baseline (2043.155 us; speedup 1.0000x reference)
//
#include <hip/hip_runtime.h>
#include <math.h>

#define S_LEN 1024
#define BATCH 64
#define EDIM  100
#define HDIM  128
#define G4    512
#define TAGS  17

// ---------------------------------------------------------------------------
// Kernel 1: embed gather + input projection for one time-chunk, both dirs.
// Local row = s*64 + b (s = chunk-local step). Forward half uses token at
// t0+s; backward half uses token at S-1-(t0+s) (the backward chain's own
// s-th step), so the scan consumes both buffers in the same local order.
// ---------------------------------------------------------------------------
__global__ __launch_bounds__(256) void proj_kernel(
    const int* __restrict__ sentence, const float* __restrict__ embed,
    const float* __restrict__ w_ih_f, const float* __restrict__ b_ih_f, const float* __restrict__ b_hh_f,
    const float* __restrict__ w_ih_b, const float* __restrict__ b_ih_b, const float* __restrict__ b_hh_b,
    float* __restrict__ xg_f, float* __restrict__ xg_b, int t0)
{
    __shared__ __align__(16) float xf[16][EDIM];
    __shared__ __align__(16) float xb[16][EDIM];
    __shared__ int tok[32];
    const int tid  = threadIdx.x;
    const int row0 = blockIdx.x * 16;

    if (tid < 32) {
        int r = tid & 15;
        int row = row0 + r;
        int s = row >> 6, b = row & 63;
        int t = (tid < 16) ? (t0 + s) : (S_LEN - 1 - (t0 + s));
        tok[tid] = sentence[b * S_LEN + t];
    }
    __syncthreads();
    for (int i = tid; i < 16 * EDIM; i += 256) {
        int r = i / EDIM, e = i - r * EDIM;
        xf[r][e] = embed[(long)tok[r] * EDIM + e];
        xb[r][e] = embed[(long)tok[16 + r] * EDIM + e];
    }
    __syncthreads();

    const float* wptr[4];
    float bias[4];
#pragma unroll
    for (int ci = 0; ci < 4; ++ci) {
        int c = tid + 256 * ci;
        if (c < G4) { wptr[ci] = w_ih_f + c * EDIM; bias[ci] = b_ih_f[c] + b_hh_f[c]; }
        else { int cb = c - G4; wptr[ci] = w_ih_b + cb * EDIM; bias[ci] = b_ih_b[cb] + b_hh_b[cb]; }
    }

    float acc[4][16];
#pragma unroll
    for (int ci = 0; ci < 4; ++ci)
#pragma unroll
        for (int r = 0; r < 16; ++r) acc[ci][r] = 0.f;

    for (int e = 0; e < EDIM; e += 4) {
        float4 w4[4];
#pragma unroll
        for (int ci = 0; ci < 4; ++ci) w4[ci] = *(const float4*)(wptr[ci] + e);
#pragma unroll
        for (int r = 0; r < 16; ++r) {
            float4 xvf = *(const float4*)&xf[r][e];
            float4 xvb = *(const float4*)&xb[r][e];
#pragma unroll
            for (int ci = 0; ci < 4; ++ci) {
                float4 xv = (ci < 2) ? xvf : xvb;
                acc[ci][r] = fmaf(w4[ci].x, xv.x, acc[ci][r]);
                acc[ci][r] = fmaf(w4[ci].y, xv.y, acc[ci][r]);
                acc[ci][r] = fmaf(w4[ci].z, xv.z, acc[ci][r]);
                acc[ci][r] = fmaf(w4[ci].w, xv.w, acc[ci][r]);
            }
        }
    }

#pragma unroll
    for (int ci = 0; ci < 4; ++ci) {
        int c = tid + 256 * ci;
#pragma unroll
        for (int r = 0; r < 16; ++r) {
            int row = row0 + r;            // local (s*64 + b)
            float v = acc[ci][r] + bias[ci];
            if (c < G4) xg_f[(long)row * G4 + c] = v;
            else        xg_b[(long)row * G4 + (c - G4)] = v;
        }
    }
}

// ---------------------------------------------------------------------------
// Kernel 2: LSTM scan over one chunk + fused emission (FC) computation.
// One workgroup per (batch, dir) chain: 128 blocks, 512 threads. Thread j
// owns gate row j of W_hh in VGPRs. Phase A: gate dots vs h_{s-1} + emission
// partials for h_{s-1} on spare lanes. Phase B: c/h update + emission reduce
// + store. (h,c) persist in global state between chunk launches.
// ---------------------------------------------------------------------------
__global__ __launch_bounds__(512, 2) void lstm_scan(
    const float* __restrict__ xg_f, const float* __restrict__ xg_b,
    const float* __restrict__ w_hh_f, const float* __restrict__ w_hh_b,
    const float* __restrict__ fc_w,
    float* __restrict__ em_f, float* __restrict__ em_b,
    float* __restrict__ h_state, float* __restrict__ c_state,
    int t0, int clen)
{
    const int j     = threadIdx.x;
    const int b     = blockIdx.x & 63;
    const int dir   = blockIdx.x >> 6;
    const int chain = blockIdx.x;

    const float* whh = dir ? w_hh_b : w_hh_f;
    const float* xg  = (dir ? xg_b : xg_f) + b * G4 + j;
    float*       em  = dir ? em_b : em_f;

    float4 w4[32];
    const float4* wrow = (const float4*)(whh + j * HDIM);
#pragma unroll
    for (int i = 0; i < 32; ++i) w4[i] = wrow[i];

    // emission partial task: threads 128..263 -> (tag, p), 16 weights in regs
    const int  ei    = j - 128;
    const bool e_act = (ei >= 0) && (ei < TAGS * 8);
    float fw[16];
    int etag = 0, ep8 = 0;
    if (e_act) {
        etag = ei >> 3; ep8 = ei & 7;
        const float* fwp = fc_w + etag * (2 * HDIM) + dir * HDIM + ep8 * 16;
#pragma unroll
        for (int q = 0; q < 16; ++q) fw[q] = fwp[q];
    }
    const int  rtag  = j - 288;                       // reducer lanes 288..304
    const bool r_act = (rtag >= 0) && (rtag < TAGS);

    __shared__ __align__(16) float h_lds[HDIM];
    __shared__ float a_lds[G4];
    __shared__ float e_lds[TAGS][8];

    float c_reg = 0.f;
    if (j < HDIM) {
        if (t0 == 0) { h_lds[j] = 0.f; }
        else { c_reg = c_state[chain * HDIM + j]; h_lds[j] = h_state[chain * HDIM + j]; }
    }
    __syncthreads();

    const bool is_g = (j >= 2 * HDIM) && (j < 3 * HDIM);   // tanh gate rows

    float xgv = xg[0];
    for (int s = 0; s < clen; ++s) {
        float xgv_next = 0.f;
        if (s + 1 < clen) xgv_next = xg[(s + 1) * (BATCH * G4)];  // prefetch

        // -------- phase A: gate dot against h_{s-1} --------
        float acc = 0.f;
#pragma unroll
        for (int i = 0; i < 32; ++i) {
            float4 h4 = *(const float4*)&h_lds[i * 4];   // broadcast read
            acc = fmaf(w4[i].x, h4.x, acc);
            acc = fmaf(w4[i].y, h4.y, acc);
            acc = fmaf(w4[i].z, h4.z, acc);
            acc = fmaf(w4[i].w, h4.w, acc);
        }
        float g = xgv + acc;
        float a = is_g ? tanhf(g) : 1.f / (1.f + expf(-g));
        a_lds[j] = a;
        if (e_act && s > 0) {                            // emission partial, h_{s-1}
            float epv = 0.f;
#pragma unroll
            for (int q = 0; q < 16; ++q) epv = fmaf(fw[q], h_lds[ep8 * 16 + q], epv);
            e_lds[etag][ep8] = epv;
        }
        __syncthreads();

        // -------- phase B: c/h update + emission reduce/store --------
        if (j < HDIM) {
            float ai = a_lds[j], af = a_lds[HDIM + j];
            float ag = a_lds[2 * HDIM + j], ao = a_lds[3 * HDIM + j];
            c_reg = af * c_reg + ai * ag;
            float hv = ao * tanhf(c_reg);
            h_lds[j] = hv;
        }
        if (r_act && s > 0) {
            const float* pp = e_lds[rtag];
            float sum = ((pp[0] + pp[1]) + (pp[2] + pp[3])) + ((pp[4] + pp[5]) + (pp[6] + pp[7]));
            int sl = s - 1;
            int t_em = dir ? (S_LEN - 1 - (t0 + sl)) : (t0 + sl);
            em[((long)t_em * BATCH + b) * TAGS + rtag] = sum;
        }
        __syncthreads();
        xgv = xgv_next;
    }

    // -------- tail: emission for h_{clen-1}; persist state --------
    if (e_act) {
        float epv = 0.f;
#pragma unroll
        for (int q = 0; q < 16; ++q) epv = fmaf(fw[q], h_lds[ep8 * 16 + q], epv);
        e_lds[etag][ep8] = epv;
    }
    if (j < HDIM) {
        c_state[chain * HDIM + j] = c_reg;
        h_state[chain * HDIM + j] = h_lds[j];
    }
    __syncthreads();
    if (r_act) {
        const float* pp = e_lds[rtag];
        float sum = ((pp[0] + pp[1]) + (pp[2] + pp[3])) + ((pp[4] + pp[5]) + (pp[6] + pp[7]));
        int sl = clen - 1;
        int t_em = dir ? (S_LEN - 1 - (t0 + sl)) : (t0 + sl);
        em[((long)t_em * BATCH + b) * TAGS + rtag] = sum;
    }
}

// ---------------------------------------------------------------------------
// Kernel 3: Viterbi forward + backtrace, one wave per batch element.
// em[t][b][tag] = em_f + em_b + fc_b. Strict-> ascending scan == jnp.argmax
// first-max tie-break; op order matches reference.
// ---------------------------------------------------------------------------
__global__ __launch_bounds__(64) void viterbi_kernel(
    const float* __restrict__ em_f, const float* __restrict__ em_b,
    const float* __restrict__ start_trans, const float* __restrict__ end_trans,
    const float* __restrict__ trans, const float* __restrict__ fc_b,
    int* __restrict__ out)
{
    const int b = blockIdx.x;
    const int lane = threadIdx.x;
    __shared__ float score[TAGS];
    __shared__ unsigned char hist[(S_LEN - 1) * TAGS];
    __shared__ int tags[S_LEN];
    const bool act = lane < TAGS;

    float tcol[TAGS];
    float fcb = act ? fc_b[lane] : 0.f;
    if (act) {
#pragma unroll
        for (int jj = 0; jj < TAGS; ++jj) tcol[jj] = trans[jj * TAGS + lane];
        float em0 = em_f[(0 * BATCH + b) * TAGS + lane] + em_b[(0 * BATCH + b) * TAGS + lane] + fcb;
        score[lane] = start_trans[lane] + em0;
    }
    __syncthreads();

    float em_cur = act ? (em_f[(1 * BATCH + b) * TAGS + lane] + em_b[(1 * BATCH + b) * TAGS + lane] + fcb) : 0.f;
    for (int s = 1; s < S_LEN; ++s) {
        float em_next = 0.f;
        if (act && (s + 1 < S_LEN)) {
            long idx = ((long)(s + 1) * BATCH + b) * TAGS + lane;
            em_next = em_f[idx] + em_b[idx] + fcb;
        }
        float best = 0.f; int bi = 0;
        if (act) {
            best = (score[0] + tcol[0]) + em_cur;
#pragma unroll
            for (int jj = 1; jj < TAGS; ++jj) {
                float v = (score[jj] + tcol[jj]) + em_cur;
                if (v > best) { best = v; bi = jj; }
            }
        }
        __syncthreads();
        if (act) { score[lane] = best; hist[(s - 1) * TAGS + lane] = (unsigned char)bi; }
        __syncthreads();
        em_cur = em_next;
    }

    if (lane == 0) {
        float bestv = score[0] + end_trans[0]; int bt = 0;
        for (int jj = 1; jj < TAGS; ++jj) {
            float v = score[jj] + end_trans[jj];
            if (v > bestv) { bestv = v; bt = jj; }
        }
        int tag = bt;
        tags[S_LEN - 1] = tag;
        for (int s = S_LEN - 2; s >= 0; --s) {
            tag = hist[s * TAGS + tag];
            tags[s] = tag;
        }
    }
    __syncthreads();
    for (int t = lane; t < S_LEN; t += 64) out[b * S_LEN + t] = tags[t];
}

// ---------------------------------------------------------------------------
extern "C" void kernel_launch(void* const* d_in, const int* in_sizes, int n_in,
                              void* d_out, int out_size, void* d_ws, size_t ws_size,
                              hipStream_t stream) {
    const int*   sentence    = (const int*)d_in[0];
    // d_in[1] = mask (all true; where(mask,...) is identity)
    const float* embed       = (const float*)d_in[2];
    const float* w_ih_f      = (const float*)d_in[3];
    const float* w_hh_f      = (const float*)d_in[4];
    const float* b_ih_f      = (const float*)d_in[5];
    const float* b_hh_f      = (const float*)d_in[6];
    const float* w_ih_b      = (const float*)d_in[7];
    const float* w_hh_b      = (const float*)d_in[8];
    const float* b_ih_b      = (const float*)d_in[9];
    const float* b_hh_b      = (const float*)d_in[10];
    const float* fc_w        = (const float*)d_in[11];
    const float* fc_b        = (const float*)d_in[12];
    const float* start_trans = (const float*)d_in[13];
    const float* end_trans   = (const float*)d_in[14];
    const float* trans       = (const float*)d_in[15];
    int* out = (int*)d_out;

    // Workspace sizing: adapt chunk length C to ws_size.
    const size_t em_elems    = (size_t)S_LEN * BATCH * TAGS;   // 1,114,112 fl
    const size_t state_elems = (size_t)128 * HDIM;             // 16,384 fl each
    static const int cands[] = {1024, 512, 256, 128, 64, 32, 16};
    int C = 16;
    for (int ci = 0; ci < 7; ++ci) {
        size_t need = ((size_t)2 * cands[ci] * BATCH * G4 + 2 * em_elems + 2 * state_elems) * 4;
        if (need <= ws_size) { C = cands[ci]; break; }
    }

    float* ws      = (float*)d_ws;
    float* xg_f    = ws;
    float* xg_b    = xg_f + (size_t)C * BATCH * G4;
    float* em_f    = xg_b + (size_t)C * BATCH * G4;
    float* em_b    = em_f + em_elems;
    float* h_state = em_b + em_elems;
    float* c_state = h_state + state_elems;

    for (int t0 = 0; t0 < S_LEN; t0 += C) {
        proj_kernel<<<(C * BATCH) / 16, 256, 0, stream>>>(
            sentence, embed, w_ih_f, b_ih_f, b_hh_f, w_ih_b, b_ih_b, b_hh_b,
            xg_f, xg_b, t0);
        lstm_scan<<<2 * BATCH, 512, 0, stream>>>(
            xg_f, xg_b, w_hh_f, w_hh_b, fc_w, em_f, em_b, h_state, c_state, t0, C);
    }
    viterbi_kernel<<<BATCH, 64, 0, stream>>>(
        em_f, em_b, start_trans, end_trans, trans, fc_b, out);
}

// Round 3
// 1942.593 us; speedup vs baseline: 1.0518x; 1.0518x over previous
//
#include <hip/hip_runtime.h>
#include <math.h>

#define S_LEN 1024
#define BATCH 64
#define EDIM  100
#define HDIM  128
#define G4    512
#define TAGS  17

// ---------------------------------------------------------------------------
// Kernel 1: embed gather + input projection for one time-chunk, both dirs.
// Local row = s*64 + b (s = chunk-local step). Forward half uses token at
// t0+s; backward half uses token at S-1-(t0+s).
// ---------------------------------------------------------------------------
__global__ __launch_bounds__(256) void proj_kernel(
    const int* __restrict__ sentence, const float* __restrict__ embed,
    const float* __restrict__ w_ih_f, const float* __restrict__ b_ih_f, const float* __restrict__ b_hh_f,
    const float* __restrict__ w_ih_b, const float* __restrict__ b_ih_b, const float* __restrict__ b_hh_b,
    float* __restrict__ xg_f, float* __restrict__ xg_b, int t0)
{
    __shared__ __align__(16) float xf[16][EDIM];
    __shared__ __align__(16) float xb[16][EDIM];
    __shared__ int tok[32];
    const int tid  = threadIdx.x;
    const int row0 = blockIdx.x * 16;

    if (tid < 32) {
        int r = tid & 15;
        int row = row0 + r;
        int s = row >> 6, b = row & 63;
        int t = (tid < 16) ? (t0 + s) : (S_LEN - 1 - (t0 + s));
        tok[tid] = sentence[b * S_LEN + t];
    }
    __syncthreads();
    for (int i = tid; i < 16 * EDIM; i += 256) {
        int r = i / EDIM, e = i - r * EDIM;
        xf[r][e] = embed[(long)tok[r] * EDIM + e];
        xb[r][e] = embed[(long)tok[16 + r] * EDIM + e];
    }
    __syncthreads();

    const float* wptr[4];
    float bias[4];
#pragma unroll
    for (int ci = 0; ci < 4; ++ci) {
        int c = tid + 256 * ci;
        if (c < G4) { wptr[ci] = w_ih_f + c * EDIM; bias[ci] = b_ih_f[c] + b_hh_f[c]; }
        else { int cb = c - G4; wptr[ci] = w_ih_b + cb * EDIM; bias[ci] = b_ih_b[cb] + b_hh_b[cb]; }
    }

    float acc[4][16];
#pragma unroll
    for (int ci = 0; ci < 4; ++ci)
#pragma unroll
        for (int r = 0; r < 16; ++r) acc[ci][r] = 0.f;

    for (int e = 0; e < EDIM; e += 4) {
        float4 w4[4];
#pragma unroll
        for (int ci = 0; ci < 4; ++ci) w4[ci] = *(const float4*)(wptr[ci] + e);
#pragma unroll
        for (int r = 0; r < 16; ++r) {
            float4 xvf = *(const float4*)&xf[r][e];
            float4 xvb = *(const float4*)&xb[r][e];
#pragma unroll
            for (int ci = 0; ci < 4; ++ci) {
                float4 xv = (ci < 2) ? xvf : xvb;
                acc[ci][r] = fmaf(w4[ci].x, xv.x, acc[ci][r]);
                acc[ci][r] = fmaf(w4[ci].y, xv.y, acc[ci][r]);
                acc[ci][r] = fmaf(w4[ci].z, xv.z, acc[ci][r]);
                acc[ci][r] = fmaf(w4[ci].w, xv.w, acc[ci][r]);
            }
        }
    }

#pragma unroll
    for (int ci = 0; ci < 4; ++ci) {
        int c = tid + 256 * ci;
#pragma unroll
        for (int r = 0; r < 16; ++r) {
            int row = row0 + r;            // local (s*64 + b)
            float v = acc[ci][r] + bias[ci];
            if (c < G4) xg_f[(long)row * G4 + c] = v;
            else        xg_b[(long)row * G4 + (c - G4)] = v;
        }
    }
}

// ---------------------------------------------------------------------------
// Kernel 2: LSTM scan over one chunk + fused emission (FC). One workgroup per
// (batch, dir) chain: 128 blocks x 512 threads. Thread j owns gate row j of
// W_hh in VGPRs; gate dot uses 4 independent accumulator chains (32 deep each)
// instead of one 128-deep fmaf chain. em layout: [B][S][TAGS]; forward dir
// folds fc_b in.
// ---------------------------------------------------------------------------
__global__ __launch_bounds__(512, 2) void lstm_scan(
    const float* __restrict__ xg_f, const float* __restrict__ xg_b,
    const float* __restrict__ w_hh_f, const float* __restrict__ w_hh_b,
    const float* __restrict__ fc_w, const float* __restrict__ fc_b,
    float* __restrict__ em_f, float* __restrict__ em_b,
    float* __restrict__ h_state, float* __restrict__ c_state,
    int t0, int clen)
{
    const int j     = threadIdx.x;
    const int b     = blockIdx.x & 63;
    const int dir   = blockIdx.x >> 6;
    const int chain = blockIdx.x;

    const float* whh = dir ? w_hh_b : w_hh_f;
    const float* xg  = (dir ? xg_b : xg_f) + b * G4 + j;
    float*       em  = dir ? em_b : em_f;

    float4 w4[32];
    const float4* wrow = (const float4*)(whh + j * HDIM);
#pragma unroll
    for (int i = 0; i < 32; ++i) w4[i] = wrow[i];

    // emission partial task: threads 128..263 -> (tag, p), 16 weights in regs
    const int  ei    = j - 128;
    const bool e_act = (ei >= 0) && (ei < TAGS * 8);
    float fw[16];
    int etag = 0, ep8 = 0;
    if (e_act) {
        etag = ei >> 3; ep8 = ei & 7;
        const float* fwp = fc_w + etag * (2 * HDIM) + dir * HDIM + ep8 * 16;
#pragma unroll
        for (int q = 0; q < 16; ++q) fw[q] = fwp[q];
    }
    const int  rtag  = j - 288;                       // reducer lanes 288..304
    const bool r_act = (rtag >= 0) && (rtag < TAGS);
    const float fcb_r = (r_act && dir == 0) ? fc_b[rtag] : 0.f;

    __shared__ __align__(16) float h_lds[HDIM];
    __shared__ float a_lds[G4];
    __shared__ float e_lds[TAGS][8];

    float c_reg = 0.f;
    if (j < HDIM) {
        if (t0 == 0) { h_lds[j] = 0.f; }
        else { c_reg = c_state[chain * HDIM + j]; h_lds[j] = h_state[chain * HDIM + j]; }
    }
    __syncthreads();

    const bool is_g = (j >= 2 * HDIM) && (j < 3 * HDIM);   // tanh gate rows

    float xgv = xg[0];
    for (int s = 0; s < clen; ++s) {
        float xgv_next = 0.f;
        if (s + 1 < clen) xgv_next = xg[(s + 1) * (BATCH * G4)];  // prefetch

        // -------- phase A: gate dot against h_{s-1}, 4 indep chains --------
        float a0 = 0.f, a1 = 0.f, a2 = 0.f, a3 = 0.f;
#pragma unroll
        for (int i = 0; i < 8; ++i) {
            float4 h4a = *(const float4*)&h_lds[i * 16 + 0];
            float4 h4b = *(const float4*)&h_lds[i * 16 + 4];
            float4 h4c = *(const float4*)&h_lds[i * 16 + 8];
            float4 h4d = *(const float4*)&h_lds[i * 16 + 12];
            a0 = fmaf(w4[i*4+0].x, h4a.x, a0); a0 = fmaf(w4[i*4+0].y, h4a.y, a0);
            a0 = fmaf(w4[i*4+0].z, h4a.z, a0); a0 = fmaf(w4[i*4+0].w, h4a.w, a0);
            a1 = fmaf(w4[i*4+1].x, h4b.x, a1); a1 = fmaf(w4[i*4+1].y, h4b.y, a1);
            a1 = fmaf(w4[i*4+1].z, h4b.z, a1); a1 = fmaf(w4[i*4+1].w, h4b.w, a1);
            a2 = fmaf(w4[i*4+2].x, h4c.x, a2); a2 = fmaf(w4[i*4+2].y, h4c.y, a2);
            a2 = fmaf(w4[i*4+2].z, h4c.z, a2); a2 = fmaf(w4[i*4+2].w, h4c.w, a2);
            a3 = fmaf(w4[i*4+3].x, h4d.x, a3); a3 = fmaf(w4[i*4+3].y, h4d.y, a3);
            a3 = fmaf(w4[i*4+3].z, h4d.z, a3); a3 = fmaf(w4[i*4+3].w, h4d.w, a3);
        }
        float g = xgv + ((a0 + a1) + (a2 + a3));
        float a = is_g ? tanhf(g) : 1.f / (1.f + expf(-g));
        a_lds[j] = a;
        if (e_act && s > 0) {                            // emission partial, h_{s-1}
            float epv = 0.f;
#pragma unroll
            for (int q = 0; q < 16; ++q) epv = fmaf(fw[q], h_lds[ep8 * 16 + q], epv);
            e_lds[etag][ep8] = epv;
        }
        __syncthreads();

        // -------- phase B: c/h update + emission reduce/store --------
        if (j < HDIM) {
            float ai = a_lds[j], af = a_lds[HDIM + j];
            float ag = a_lds[2 * HDIM + j], ao = a_lds[3 * HDIM + j];
            c_reg = af * c_reg + ai * ag;
            float hv = ao * tanhf(c_reg);
            h_lds[j] = hv;
        }
        if (r_act && s > 0) {
            const float* pp = e_lds[rtag];
            float sum = ((pp[0] + pp[1]) + (pp[2] + pp[3])) + ((pp[4] + pp[5]) + (pp[6] + pp[7]));
            int sl = s - 1;
            int t_em = dir ? (S_LEN - 1 - (t0 + sl)) : (t0 + sl);
            em[((long)b * S_LEN + t_em) * TAGS + rtag] = sum + fcb_r;
        }
        __syncthreads();
        xgv = xgv_next;
    }

    // -------- tail: emission for h_{clen-1}; persist state --------
    if (e_act) {
        float epv = 0.f;
#pragma unroll
        for (int q = 0; q < 16; ++q) epv = fmaf(fw[q], h_lds[ep8 * 16 + q], epv);
        e_lds[etag][ep8] = epv;
    }
    if (j < HDIM) {
        c_state[chain * HDIM + j] = c_reg;
        h_state[chain * HDIM + j] = h_lds[j];
    }
    __syncthreads();
    if (r_act) {
        const float* pp = e_lds[rtag];
        float sum = ((pp[0] + pp[1]) + (pp[2] + pp[3])) + ((pp[4] + pp[5]) + (pp[6] + pp[7]));
        int sl = clen - 1;
        int t_em = dir ? (S_LEN - 1 - (t0 + sl)) : (t0 + sl);
        em[((long)b * S_LEN + t_em) * TAGS + rtag] = sum + fcb_r;
    }
}

// ---------------------------------------------------------------------------
// Kernel 3: Viterbi forward + backtrace, one wave per batch element.
// Entire summed emission table staged in LDS upfront (coalesced float4);
// leftmost-max tree (>= picks left) == jnp.argmax first-max tie-break.
// Value op order matches reference: (score[j] + trans[j][c]) + em[c].
// ---------------------------------------------------------------------------
#define CMB(vL, iL, vR, iR, vO, iO) \
    { bool _p = (vL) >= (vR); vO = _p ? (vL) : (vR); iO = _p ? (iL) : (iR); }

__global__ __launch_bounds__(64) void viterbi_kernel(
    const float* __restrict__ em_f, const float* __restrict__ em_b,
    const float* __restrict__ start_trans, const float* __restrict__ end_trans,
    const float* __restrict__ trans, int* __restrict__ out)
{
    const int b = blockIdx.x;
    const int lane = threadIdx.x;
    __shared__ __align__(16) float e_lds[S_LEN * TAGS];      // 68 KB
    __shared__ float score[TAGS];
    __shared__ unsigned char hist[(S_LEN - 1) * TAGS];
    __shared__ int tags[S_LEN];

    // stage summed emissions: e = em_f (fc_b already folded) + em_b
    {
        const float4* ef4 = (const float4*)(em_f + (long)b * S_LEN * TAGS);
        const float4* eb4 = (const float4*)(em_b + (long)b * S_LEN * TAGS);
        float4* el4 = (float4*)e_lds;
        for (int i = lane; i < (S_LEN * TAGS) / 4; i += 64) {
            float4 x = ef4[i], y = eb4[i];
            float4 z; z.x = x.x + y.x; z.y = x.y + y.y; z.z = x.z + y.z; z.w = x.w + y.w;
            el4[i] = z;
        }
    }
    const bool act = lane < TAGS;
    float tcol[TAGS];
    if (act) {
#pragma unroll
        for (int jj = 0; jj < TAGS; ++jj) tcol[jj] = trans[jj * TAGS + lane];
    }
    __syncthreads();
    if (act) score[lane] = start_trans[lane] + e_lds[lane];
    __syncthreads();

    for (int s = 1; s < S_LEN; ++s) {
        float best = 0.f; int bi = 0;
        if (act) {
            float em_c = e_lds[s * TAGS + lane];
            float sv[TAGS];
#pragma unroll
            for (int jj = 0; jj < TAGS; ++jj) sv[jj] = (score[jj] + tcol[jj]) + em_c;
            // leftmost-max tree (exact first-max semantics)
            float m[8]; int mi[8];
#pragma unroll
            for (int k = 0; k < 8; ++k) CMB(sv[2*k], 2*k, sv[2*k+1], 2*k+1, m[k], mi[k]);
            float n[4]; int ni[4];
#pragma unroll
            for (int k = 0; k < 4; ++k) CMB(m[2*k], mi[2*k], m[2*k+1], mi[2*k+1], n[k], ni[k]);
            float p0, p1; int pi0, pi1;
            CMB(n[0], ni[0], n[1], ni[1], p0, pi0);
            CMB(n[2], ni[2], n[3], ni[3], p1, pi1);
            float q; int qi;
            CMB(p0, pi0, p1, pi1, q, qi);
            CMB(q, qi, sv[16], 16, best, bi);
        }
        __syncthreads();
        if (act) { score[lane] = best; hist[(s - 1) * TAGS + lane] = (unsigned char)bi; }
        __syncthreads();
    }

    if (lane == 0) {
        float bestv = score[0] + end_trans[0]; int bt = 0;
        for (int jj = 1; jj < TAGS; ++jj) {
            float v = score[jj] + end_trans[jj];
            if (v > bestv) { bestv = v; bt = jj; }
        }
        int tag = bt;
        tags[S_LEN - 1] = tag;
        for (int s = S_LEN - 2; s >= 0; --s) {
            tag = hist[s * TAGS + tag];
            tags[s] = tag;
        }
    }
    __syncthreads();
    for (int t = lane; t < S_LEN; t += 64) out[b * S_LEN + t] = tags[t];
}

// ---------------------------------------------------------------------------
extern "C" void kernel_launch(void* const* d_in, const int* in_sizes, int n_in,
                              void* d_out, int out_size, void* d_ws, size_t ws_size,
                              hipStream_t stream) {
    const int*   sentence    = (const int*)d_in[0];
    // d_in[1] = mask (all true; where(mask,...) is identity)
    const float* embed       = (const float*)d_in[2];
    const float* w_ih_f      = (const float*)d_in[3];
    const float* w_hh_f      = (const float*)d_in[4];
    const float* b_ih_f      = (const float*)d_in[5];
    const float* b_hh_f      = (const float*)d_in[6];
    const float* w_ih_b      = (const float*)d_in[7];
    const float* w_hh_b      = (const float*)d_in[8];
    const float* b_ih_b      = (const float*)d_in[9];
    const float* b_hh_b      = (const float*)d_in[10];
    const float* fc_w        = (const float*)d_in[11];
    const float* fc_b        = (const float*)d_in[12];
    const float* start_trans = (const float*)d_in[13];
    const float* end_trans   = (const float*)d_in[14];
    const float* trans       = (const float*)d_in[15];
    int* out = (int*)d_out;

    // Workspace sizing: adapt chunk length C to ws_size.
    const size_t em_elems    = (size_t)S_LEN * BATCH * TAGS;   // 1,114,112 fl
    const size_t state_elems = (size_t)128 * HDIM;             // 16,384 fl each
    static const int cands[] = {1024, 512, 256, 128, 64, 32, 16};
    int C = 16;
    for (int ci = 0; ci < 7; ++ci) {
        size_t need = ((size_t)2 * cands[ci] * BATCH * G4 + 2 * em_elems + 2 * state_elems) * 4;
        if (need <= ws_size) { C = cands[ci]; break; }
    }

    float* ws      = (float*)d_ws;
    float* xg_f    = ws;
    float* xg_b    = xg_f + (size_t)C * BATCH * G4;
    float* em_f    = xg_b + (size_t)C * BATCH * G4;
    float* em_b    = em_f + em_elems;
    float* h_state = em_b + em_elems;
    float* c_state = h_state + state_elems;

    for (int t0 = 0; t0 < S_LEN; t0 += C) {
        proj_kernel<<<(C * BATCH) / 16, 256, 0, stream>>>(
            sentence, embed, w_ih_f, b_ih_f, b_hh_f, w_ih_b, b_ih_b, b_hh_b,
            xg_f, xg_b, t0);
        lstm_scan<<<2 * BATCH, 512, 0, stream>>>(
            xg_f, xg_b, w_hh_f, w_hh_b, fc_w, fc_b, em_f, em_b, h_state, c_state, t0, C);
    }
    viterbi_kernel<<<BATCH, 64, 0, stream>>>(
        em_f, em_b, start_trans, end_trans, trans, out);
}

// Round 4
// 1836.070 us; speedup vs baseline: 1.1128x; 1.0580x over previous
//
#include <hip/hip_runtime.h>
#include <math.h>

#define S_LEN 1024
#define BATCH 64
#define EDIM  100
#define HDIM  128
#define G4    512
#define TAGS  17

// fast transcendentals: v_exp_f32 / v_rcp_f32 based, abs err ~1e-7, saturate correctly
__device__ __forceinline__ float fast_sigmoid(float g) {
    return __builtin_amdgcn_rcpf(1.f + __expf(-g));
}
__device__ __forceinline__ float fast_tanh(float g) {
    return 1.f - 2.f * __builtin_amdgcn_rcpf(__expf(2.f * g) + 1.f);
}

// ---------------------------------------------------------------------------
// Kernel 1: embed gather + input projection for one time-chunk, both dirs.
// ---------------------------------------------------------------------------
__global__ __launch_bounds__(256) void proj_kernel(
    const int* __restrict__ sentence, const float* __restrict__ embed,
    const float* __restrict__ w_ih_f, const float* __restrict__ b_ih_f, const float* __restrict__ b_hh_f,
    const float* __restrict__ w_ih_b, const float* __restrict__ b_ih_b, const float* __restrict__ b_hh_b,
    float* __restrict__ xg_f, float* __restrict__ xg_b, int t0)
{
    __shared__ __align__(16) float xf[16][EDIM];
    __shared__ __align__(16) float xb[16][EDIM];
    __shared__ int tok[32];
    const int tid  = threadIdx.x;
    const int row0 = blockIdx.x * 16;

    if (tid < 32) {
        int r = tid & 15;
        int row = row0 + r;
        int s = row >> 6, b = row & 63;
        int t = (tid < 16) ? (t0 + s) : (S_LEN - 1 - (t0 + s));
        tok[tid] = sentence[b * S_LEN + t];
    }
    __syncthreads();
    for (int i = tid; i < 16 * EDIM; i += 256) {
        int r = i / EDIM, e = i - r * EDIM;
        xf[r][e] = embed[(long)tok[r] * EDIM + e];
        xb[r][e] = embed[(long)tok[16 + r] * EDIM + e];
    }
    __syncthreads();

    const float* wptr[4];
    float bias[4];
#pragma unroll
    for (int ci = 0; ci < 4; ++ci) {
        int c = tid + 256 * ci;
        if (c < G4) { wptr[ci] = w_ih_f + c * EDIM; bias[ci] = b_ih_f[c] + b_hh_f[c]; }
        else { int cb = c - G4; wptr[ci] = w_ih_b + cb * EDIM; bias[ci] = b_ih_b[cb] + b_hh_b[cb]; }
    }

    float acc[4][16];
#pragma unroll
    for (int ci = 0; ci < 4; ++ci)
#pragma unroll
        for (int r = 0; r < 16; ++r) acc[ci][r] = 0.f;

    for (int e = 0; e < EDIM; e += 4) {
        float4 w4[4];
#pragma unroll
        for (int ci = 0; ci < 4; ++ci) w4[ci] = *(const float4*)(wptr[ci] + e);
#pragma unroll
        for (int r = 0; r < 16; ++r) {
            float4 xvf = *(const float4*)&xf[r][e];
            float4 xvb = *(const float4*)&xb[r][e];
#pragma unroll
            for (int ci = 0; ci < 4; ++ci) {
                float4 xv = (ci < 2) ? xvf : xvb;
                acc[ci][r] = fmaf(w4[ci].x, xv.x, acc[ci][r]);
                acc[ci][r] = fmaf(w4[ci].y, xv.y, acc[ci][r]);
                acc[ci][r] = fmaf(w4[ci].z, xv.z, acc[ci][r]);
                acc[ci][r] = fmaf(w4[ci].w, xv.w, acc[ci][r]);
            }
        }
    }

#pragma unroll
    for (int ci = 0; ci < 4; ++ci) {
        int c = tid + 256 * ci;
#pragma unroll
        for (int r = 0; r < 16; ++r) {
            int row = row0 + r;            // local (s*64 + b)
            float v = acc[ci][r] + bias[ci];
            if (c < G4) xg_f[(long)row * G4 + c] = v;
            else        xg_b[(long)row * G4 + (c - G4)] = v;
        }
    }
}

// ---------------------------------------------------------------------------
// Kernel 2: LSTM scan over one chunk + fused emission (FC). One workgroup per
// (batch, dir) chain: 128 blocks x 512 threads. xg prefetch depth 2; fast
// exp/rcp transcendentals. em layout: [B][S][TAGS]; forward dir folds fc_b.
// ---------------------------------------------------------------------------
__global__ __launch_bounds__(512, 2) void lstm_scan(
    const float* __restrict__ xg_f, const float* __restrict__ xg_b,
    const float* __restrict__ w_hh_f, const float* __restrict__ w_hh_b,
    const float* __restrict__ fc_w, const float* __restrict__ fc_b,
    float* __restrict__ em_f, float* __restrict__ em_b,
    float* __restrict__ h_state, float* __restrict__ c_state,
    int t0, int clen)
{
    const int j     = threadIdx.x;
    const int b     = blockIdx.x & 63;
    const int dir   = blockIdx.x >> 6;
    const int chain = blockIdx.x;

    const float* whh = dir ? w_hh_b : w_hh_f;
    const float* xg  = (dir ? xg_b : xg_f) + b * G4 + j;
    float*       em  = dir ? em_b : em_f;

    float4 w4[32];
    const float4* wrow = (const float4*)(whh + j * HDIM);
#pragma unroll
    for (int i = 0; i < 32; ++i) w4[i] = wrow[i];

    // emission partial task: threads 128..263 -> (tag, p), 16 weights in regs
    const int  ei    = j - 128;
    const bool e_act = (ei >= 0) && (ei < TAGS * 8);
    float fw[16];
    int etag = 0, ep8 = 0;
    if (e_act) {
        etag = ei >> 3; ep8 = ei & 7;
        const float* fwp = fc_w + etag * (2 * HDIM) + dir * HDIM + ep8 * 16;
#pragma unroll
        for (int q = 0; q < 16; ++q) fw[q] = fwp[q];
    }
    const int  rtag  = j - 288;                       // reducer lanes 288..304
    const bool r_act = (rtag >= 0) && (rtag < TAGS);
    const float fcb_r = (r_act && dir == 0) ? fc_b[rtag] : 0.f;

    __shared__ __align__(16) float h_lds[HDIM];
    __shared__ float a_lds[G4];
    __shared__ float e_lds[TAGS][8];

    float c_reg = 0.f;
    if (j < HDIM) {
        if (t0 == 0) { h_lds[j] = 0.f; }
        else { c_reg = c_state[chain * HDIM + j]; h_lds[j] = h_state[chain * HDIM + j]; }
    }
    __syncthreads();

    const bool is_g = (j >= 2 * HDIM) && (j < 3 * HDIM);   // tanh gate rows

    float xgv  = xg[0];
    float xgv1 = (clen > 1) ? xg[BATCH * G4] : 0.f;
    for (int s = 0; s < clen; ++s) {
        float xgv2 = 0.f;
        if (s + 2 < clen) xgv2 = xg[(s + 2) * (BATCH * G4)];   // depth-2 prefetch

        // -------- phase A: gate dot against h_{s-1}, 4 indep chains --------
        float a0 = 0.f, a1 = 0.f, a2 = 0.f, a3 = 0.f;
#pragma unroll
        for (int i = 0; i < 8; ++i) {
            float4 h4a = *(const float4*)&h_lds[i * 16 + 0];
            float4 h4b = *(const float4*)&h_lds[i * 16 + 4];
            float4 h4c = *(const float4*)&h_lds[i * 16 + 8];
            float4 h4d = *(const float4*)&h_lds[i * 16 + 12];
            a0 = fmaf(w4[i*4+0].x, h4a.x, a0); a0 = fmaf(w4[i*4+0].y, h4a.y, a0);
            a0 = fmaf(w4[i*4+0].z, h4a.z, a0); a0 = fmaf(w4[i*4+0].w, h4a.w, a0);
            a1 = fmaf(w4[i*4+1].x, h4b.x, a1); a1 = fmaf(w4[i*4+1].y, h4b.y, a1);
            a1 = fmaf(w4[i*4+1].z, h4b.z, a1); a1 = fmaf(w4[i*4+1].w, h4b.w, a1);
            a2 = fmaf(w4[i*4+2].x, h4c.x, a2); a2 = fmaf(w4[i*4+2].y, h4c.y, a2);
            a2 = fmaf(w4[i*4+2].z, h4c.z, a2); a2 = fmaf(w4[i*4+2].w, h4c.w, a2);
            a3 = fmaf(w4[i*4+3].x, h4d.x, a3); a3 = fmaf(w4[i*4+3].y, h4d.y, a3);
            a3 = fmaf(w4[i*4+3].z, h4d.z, a3); a3 = fmaf(w4[i*4+3].w, h4d.w, a3);
        }
        float g = xgv + ((a0 + a1) + (a2 + a3));
        float a = is_g ? fast_tanh(g) : fast_sigmoid(g);
        a_lds[j] = a;
        if (e_act && s > 0) {                            // emission partial, h_{s-1}
            float epv = 0.f;
#pragma unroll
            for (int q = 0; q < 16; ++q) epv = fmaf(fw[q], h_lds[ep8 * 16 + q], epv);
            e_lds[etag][ep8] = epv;
        }
        __syncthreads();

        // -------- phase B: c/h update + emission reduce/store --------
        if (j < HDIM) {
            float ai = a_lds[j], af = a_lds[HDIM + j];
            float ag = a_lds[2 * HDIM + j], ao = a_lds[3 * HDIM + j];
            c_reg = af * c_reg + ai * ag;
            float hv = ao * fast_tanh(c_reg);
            h_lds[j] = hv;
        }
        if (r_act && s > 0) {
            const float* pp = e_lds[rtag];
            float sum = ((pp[0] + pp[1]) + (pp[2] + pp[3])) + ((pp[4] + pp[5]) + (pp[6] + pp[7]));
            int sl = s - 1;
            int t_em = dir ? (S_LEN - 1 - (t0 + sl)) : (t0 + sl);
            em[((long)b * S_LEN + t_em) * TAGS + rtag] = sum + fcb_r;
        }
        __syncthreads();
        xgv = xgv1; xgv1 = xgv2;
    }

    // -------- tail: emission for h_{clen-1}; persist state --------
    if (e_act) {
        float epv = 0.f;
#pragma unroll
        for (int q = 0; q < 16; ++q) epv = fmaf(fw[q], h_lds[ep8 * 16 + q], epv);
        e_lds[etag][ep8] = epv;
    }
    if (j < HDIM) {
        c_state[chain * HDIM + j] = c_reg;
        h_state[chain * HDIM + j] = h_lds[j];
    }
    __syncthreads();
    if (r_act) {
        const float* pp = e_lds[rtag];
        float sum = ((pp[0] + pp[1]) + (pp[2] + pp[3])) + ((pp[4] + pp[5]) + (pp[6] + pp[7]));
        int sl = clen - 1;
        int t_em = dir ? (S_LEN - 1 - (t0 + sl)) : (t0 + sl);
        em[((long)b * S_LEN + t_em) * TAGS + rtag] = sum + fcb_r;
    }
}

// ---------------------------------------------------------------------------
// Kernel 3: Viterbi, one wave per batch. Score lives in registers (lane c owns
// score[c]); cross-lane exchange via __shfl -> ZERO barriers in the hot loop.
// Values/tie-breaks bit-identical to the LDS version: (score[j]+tcol[j])+em_c,
// leftmost-max tree (>= picks left) == jnp.argmax first-max.
// ---------------------------------------------------------------------------
#define CMB(vL, iL, vR, iR, vO, iO) \
    { bool _p = (vL) >= (vR); vO = _p ? (vL) : (vR); iO = _p ? (iL) : (iR); }

__global__ __launch_bounds__(64) void viterbi_kernel(
    const float* __restrict__ em_f, const float* __restrict__ em_b,
    const float* __restrict__ start_trans, const float* __restrict__ end_trans,
    const float* __restrict__ trans, int* __restrict__ out)
{
    const int b = blockIdx.x;
    const int lane = threadIdx.x;
    __shared__ __align__(16) float e_lds[S_LEN * TAGS];      // 68 KB
    __shared__ unsigned char hist[(S_LEN - 1) * TAGS];
    __shared__ int tags[S_LEN];

    // stage summed emissions: e = em_f (fc_b folded) + em_b, coalesced float4
    {
        const float4* ef4 = (const float4*)(em_f + (long)b * S_LEN * TAGS);
        const float4* eb4 = (const float4*)(em_b + (long)b * S_LEN * TAGS);
        float4* el4 = (float4*)e_lds;
        for (int i = lane; i < (S_LEN * TAGS) / 4; i += 64) {
            float4 x = ef4[i], y = eb4[i];
            float4 z; z.x = x.x + y.x; z.y = x.y + y.y; z.z = x.z + y.z; z.w = x.w + y.w;
            el4[i] = z;
        }
    }
    const int cl = (lane < TAGS) ? lane : 0;    // clamp: lanes >=17 shadow lane 0
    float tcol[TAGS], etr[TAGS];
#pragma unroll
    for (int jj = 0; jj < TAGS; ++jj) {
        tcol[jj] = trans[jj * TAGS + cl];
        etr[jj]  = end_trans[jj];
    }
    __syncthreads();

    float sc = start_trans[cl] + e_lds[cl];     // lane's own score[c]

    float em_cur = e_lds[1 * TAGS + cl];
    for (int s = 1; s < S_LEN; ++s) {
        int sn = (s + 1 < S_LEN) ? (s + 1) : s;
        float em_next = e_lds[sn * TAGS + cl];  // independent of score chain

        float sv[TAGS];
#pragma unroll
        for (int jj = 0; jj < TAGS; ++jj) {
            float sj = __shfl(sc, jj);
            sv[jj] = (sj + tcol[jj]) + em_cur;
        }
        float m[8]; int mi[8];
#pragma unroll
        for (int k = 0; k < 8; ++k) CMB(sv[2*k], 2*k, sv[2*k+1], 2*k+1, m[k], mi[k]);
        float n[4]; int ni[4];
#pragma unroll
        for (int k = 0; k < 4; ++k) CMB(m[2*k], mi[2*k], m[2*k+1], mi[2*k+1], n[k], ni[k]);
        float p0, p1; int pi0, pi1;
        CMB(n[0], ni[0], n[1], ni[1], p0, pi0);
        CMB(n[2], ni[2], n[3], ni[3], p1, pi1);
        float q; int qi;
        CMB(p0, pi0, p1, pi1, q, qi);
        float best; int bi;
        CMB(q, qi, sv[16], 16, best, bi);

        sc = best;
        if (lane < TAGS) hist[(s - 1) * TAGS + lane] = (unsigned char)bi;
        em_cur = em_next;
    }

    // final argmax over score + end_trans (all lanes compute, identical result)
    float ev[TAGS];
#pragma unroll
    for (int jj = 0; jj < TAGS; ++jj) ev[jj] = __shfl(sc, jj) + etr[jj];
    {
        float m[8]; int mi[8];
#pragma unroll
        for (int k = 0; k < 8; ++k) CMB(ev[2*k], 2*k, ev[2*k+1], 2*k+1, m[k], mi[k]);
        float n[4]; int ni[4];
#pragma unroll
        for (int k = 0; k < 4; ++k) CMB(m[2*k], mi[2*k], m[2*k+1], mi[2*k+1], n[k], ni[k]);
        float p0, p1; int pi0, pi1;
        CMB(n[0], ni[0], n[1], ni[1], p0, pi0);
        CMB(n[2], ni[2], n[3], ni[3], p1, pi1);
        float q; int qi;
        CMB(p0, pi0, p1, pi1, q, qi);
        float bestv; int bt;
        CMB(q, qi, ev[16], 16, bestv, bt);
        (void)bestv;

        __syncthreads();                         // hist writes visible
        if (lane == 0) {
            int tag = bt;
            tags[S_LEN - 1] = tag;
            for (int s = S_LEN - 2; s >= 0; --s) {
                tag = hist[s * TAGS + tag];
                tags[s] = tag;
            }
        }
    }
    __syncthreads();
    for (int t = lane; t < S_LEN; t += 64) out[b * S_LEN + t] = tags[t];
}

// ---------------------------------------------------------------------------
extern "C" void kernel_launch(void* const* d_in, const int* in_sizes, int n_in,
                              void* d_out, int out_size, void* d_ws, size_t ws_size,
                              hipStream_t stream) {
    const int*   sentence    = (const int*)d_in[0];
    // d_in[1] = mask (all true; where(mask,...) is identity)
    const float* embed       = (const float*)d_in[2];
    const float* w_ih_f      = (const float*)d_in[3];
    const float* w_hh_f      = (const float*)d_in[4];
    const float* b_ih_f      = (const float*)d_in[5];
    const float* b_hh_f      = (const float*)d_in[6];
    const float* w_ih_b      = (const float*)d_in[7];
    const float* w_hh_b      = (const float*)d_in[8];
    const float* b_ih_b      = (const float*)d_in[9];
    const float* b_hh_b      = (const float*)d_in[10];
    const float* fc_w        = (const float*)d_in[11];
    const float* fc_b        = (const float*)d_in[12];
    const float* start_trans = (const float*)d_in[13];
    const float* end_trans   = (const float*)d_in[14];
    const float* trans       = (const float*)d_in[15];
    int* out = (int*)d_out;

    // Workspace sizing: adapt chunk length C to ws_size.
    const size_t em_elems    = (size_t)S_LEN * BATCH * TAGS;
    const size_t state_elems = (size_t)128 * HDIM;
    static const int cands[] = {1024, 512, 256, 128, 64, 32, 16};
    int C = 16;
    for (int ci = 0; ci < 7; ++ci) {
        size_t need = ((size_t)2 * cands[ci] * BATCH * G4 + 2 * em_elems + 2 * state_elems) * 4;
        if (need <= ws_size) { C = cands[ci]; break; }
    }

    float* ws      = (float*)d_ws;
    float* xg_f    = ws;
    float* xg_b    = xg_f + (size_t)C * BATCH * G4;
    float* em_f    = xg_b + (size_t)C * BATCH * G4;
    float* em_b    = em_f + em_elems;
    float* h_state = em_b + em_elems;
    float* c_state = h_state + state_elems;

    for (int t0 = 0; t0 < S_LEN; t0 += C) {
        proj_kernel<<<(C * BATCH) / 16, 256, 0, stream>>>(
            sentence, embed, w_ih_f, b_ih_f, b_hh_f, w_ih_b, b_ih_b, b_hh_b,
            xg_f, xg_b, t0);
        lstm_scan<<<2 * BATCH, 512, 0, stream>>>(
            xg_f, xg_b, w_hh_f, w_hh_b, fc_w, fc_b, em_f, em_b, h_state, c_state, t0, C);
    }
    viterbi_kernel<<<BATCH, 64, 0, stream>>>(
        em_f, em_b, start_trans, end_trans, trans, out);
}